// Round 1
// baseline (84.340 us; speedup 1.0000x reference)
//
#include <hip/hip_runtime.h>

#define W 126
#define NPIX 15876      // 126*126
#define NQUAD 3969      // NPIX/4
#define NB 16
#define NCH 8
#define NCLS 100

// ---------------------------------------------------------------------------
// Kernel A: contract logits over classes with (sigma_x, sigma_y, opacity, rho)
// and reduce into 196 accumulators keyed by slot = (y%7)*7 + (x%7).
// Each thread owns one float4 pixel-quad; blockIdx.y splits classes 4x25.
// ---------------------------------------------------------------------------
__global__ __launch_bounds__(256) void ga_reduce(
    const float* __restrict__ logits,
    const float* __restrict__ sx, const float* __restrict__ sy,
    const float* __restrict__ op, const float* __restrict__ rho,
    float* __restrict__ acc) {
  __shared__ float s_par[4][NCLS];
  __shared__ float s_acc[196];
  const int t = threadIdx.x;
  for (int i = t; i < NCLS; i += 256) {
    s_par[0][i] = sx[i];
    s_par[1][i] = sy[i];
    s_par[2][i] = op[i];
    s_par[3][i] = rho[i];
  }
  for (int i = t; i < 196; i += 256) s_acc[i] = 0.f;
  __syncthreads();

  const int q = blockIdx.x * 256 + t;
  if (q < NB * NQUAD) {
    const int b  = q / NQUAD;
    const int pq = q - b * NQUAD;
    const float4* base = reinterpret_cast<const float4*>(logits) +
                         (size_t)b * NCLS * NQUAD + pq;
    const int c0 = blockIdx.y * 25;
    float a00=0.f,a01=0.f,a02=0.f,a03=0.f;
    float a10=0.f,a11=0.f,a12=0.f,a13=0.f;
    float a20=0.f,a21=0.f,a22=0.f,a23=0.f;
    float a30=0.f,a31=0.f,a32=0.f,a33=0.f;
#pragma unroll
    for (int cc = 0; cc < 25; ++cc) {
      const int c = c0 + cc;
      const float4 v = base[(size_t)c * NQUAD];
      const float p0 = s_par[0][c], p1 = s_par[1][c];
      const float p2 = s_par[2][c], p3 = s_par[3][c];
      a00 += v.x*p0; a01 += v.y*p0; a02 += v.z*p0; a03 += v.w*p0;
      a10 += v.x*p1; a11 += v.y*p1; a12 += v.z*p1; a13 += v.w*p1;
      a20 += v.x*p2; a21 += v.y*p2; a22 += v.z*p2; a23 += v.w*p2;
      a30 += v.x*p3; a31 += v.y*p3; a32 += v.z*p3; a33 += v.w*p3;
    }
    const int pix = pq * 4;
    int yy = pix / W;
    int xx = pix - yy * W;
#define PUSH(A0,A1,A2,A3)                                            \
    {                                                                \
      const int slot = (yy % 7) * 7 + (xx % 7);                      \
      atomicAdd(&s_acc[slot],       A0);                             \
      atomicAdd(&s_acc[49 + slot],  A1);                             \
      atomicAdd(&s_acc[98 + slot],  A2);                             \
      atomicAdd(&s_acc[147 + slot], A3);                             \
      if (++xx == W) { xx = 0; ++yy; }                               \
    }
    PUSH(a00, a10, a20, a30)
    PUSH(a01, a11, a21, a31)
    PUSH(a02, a12, a22, a32)
    PUSH(a03, a13, a23, a33)
#undef PUSH
  }
  __syncthreads();
  for (int i = t; i < 196; i += 256) {
    const float v = s_acc[i];
    if (v != 0.f) atomicAdd(&acc[i], v);
  }
}

// ---------------------------------------------------------------------------
// Kernel B: per-point gaussian kernel build + bilinear shift + opacity weight.
// Writes MT[q*52 + p] = wop[p] * kt[p][q], rows padded to 52 floats.
// One block, threads p = point index (49 active).
// ---------------------------------------------------------------------------
__global__ __launch_bounds__(64) void gb_build(const float* __restrict__ acc,
                                               float* __restrict__ MT) {
  __shared__ float s_kern[49][49];  // padded 7x7 kernel per point
  const int p = threadIdx.x;
  // zero the pad columns (49..51) of each row; real columns written below
  for (int i = p; i < 49; i += 64) {
    MT[i * 52 + 49] = 0.f;
    MT[i * 52 + 50] = 0.f;
    MT[i * 52 + 51] = 0.f;
  }
  if (p < 49) {
    const float inv = 1.0f / 5184.0f;   // mean over BL = 16*18*18
    const float wsx = acc[p]        * inv;
    const float wsy = acc[49 + p]   * inv;
    const float wop = acc[98 + p]   * inv;
    const float wrh = acc[147 + p]  * inv;
    const float av = wsx * wsx + 1e-5f;
    const float dv = wsy * wsy + 1e-5f;
    const float bv = wrh * wsx * wsy;
    const float det = av * dv - bv * bv;
    const float norm = 1.0f / (6.283185307179586f * sqrtf(det));
    float tmp[5][5];
    float mx = 0.f;
#pragma unroll
    for (int i = 0; i < 5; ++i) {
      const float gx = -5.0f + 2.5f * (float)i;
#pragma unroll
      for (int j = 0; j < 5; ++j) {
        const float gy = -5.0f + 2.5f * (float)j;
        const float z = -0.5f * (dv*gx*gx - 2.0f*bv*gx*gy + av*gy*gy) / det;
        const float v = expf(z) * norm;
        tmp[i][j] = v;
        mx = fmaxf(mx, v);
      }
    }
    const float rmx = 1.0f / mx;
#pragma unroll
    for (int i = 0; i < 49; ++i) s_kern[p][i] = 0.f;
#pragma unroll
    for (int i = 0; i < 5; ++i)
#pragma unroll
      for (int j = 0; j < 5; ++j)
        s_kern[p][(i + 1) * 7 + (j + 1)] = tmp[i][j] * rmx;

    // bilinear shift (grid_sample, zeros padding, pure translation)
    const int yp = p / 7, xp = p % 7;
    const float tx = (1.0f - (2.0f * (float)xp) / 7.0f) * 3.0f;
    const float ty = (1.0f - (2.0f * (float)yp) / 7.0f) * 3.0f;
    for (int i = 0; i < 7; ++i) {
      const float yq  = (float)i + ty;
      const float y0f = floorf(yq);
      const float fy  = yq - y0f;
      const int   y0  = (int)y0f;
      for (int j = 0; j < 7; ++j) {
        const float xq  = (float)j + tx;
        const float x0f = floorf(xq);
        const float fx  = xq - x0f;
        const int   x0  = (int)x0f;
        float v = 0.f;
        for (int dy = 0; dy < 2; ++dy) {
          const int yi = y0 + dy;
          if (yi < 0 || yi > 6) continue;
          const float wy = dy ? fy : (1.0f - fy);
          for (int dx = 0; dx < 2; ++dx) {
            const int xi = x0 + dx;
            if (xi < 0 || xi > 6) continue;
            const float wx = dx ? fx : (1.0f - fx);
            v += wy * wx * s_kern[p][yi * 7 + xi];
          }
        }
        MT[(i * 7 + j) * 52 + p] = wop * v;
      }
    }
  }
}

// ---------------------------------------------------------------------------
// Kernel C: splat. One block per (plane, patch-row) strip of 7x126 pixels.
// out[q] = dot49(feat_patch, MT_row[q]); both staged in LDS, float4 reads.
// ---------------------------------------------------------------------------
__global__ __launch_bounds__(256) void gc_splat(
    const float* __restrict__ feat, const float* __restrict__ MT,
    float* __restrict__ out) {
  __shared__ __align__(16) float s_mt[49 * 52];
  __shared__ __align__(16) float s_fp[18 * 52];
  const int t = threadIdx.x;
  for (int i = t; i < 49 * 52; i += 256) s_mt[i] = MT[i];
  const int blk   = blockIdx.x;           // plane*18 + patch_row
  const int plane = blk / 18;
  const int pr    = blk - plane * 18;
  const float* src = feat + (size_t)plane * NPIX + (size_t)pr * 7 * W;
  for (int i = t; i < 882; i += 256) {
    const int py = i / W;
    const int xx = i - py * W;
    const int pc = xx / 7;
    const int px = xx - pc * 7;
    s_fp[pc * 52 + py * 7 + px] = src[i];
  }
  __syncthreads();
  float* dst = out + (size_t)plane * NPIX + (size_t)pr * 7 * W;
  for (int i = t; i < 882; i += 256) {
    const int yy = i / W;
    const int xx = i - yy * W;
    const int pc = xx / 7;
    const int q  = yy * 7 + (xx - pc * 7);
    const float4* mv = reinterpret_cast<const float4*>(s_mt + q * 52);
    const float4* fv = reinterpret_cast<const float4*>(s_fp + pc * 52);
    float s = 0.f;
#pragma unroll
    for (int r = 0; r < 12; ++r) {
      const float4 m = mv[r];
      const float4 f = fv[r];
      s += f.x * m.x + f.y * m.y + f.z * m.z + f.w * m.w;
    }
    s += s_fp[pc * 52 + 48] * s_mt[q * 52 + 48];
    dst[i] = s;
  }
}

extern "C" void kernel_launch(void* const* d_in, const int* in_sizes, int n_in,
                              void* d_out, int out_size, void* d_ws, size_t ws_size,
                              hipStream_t stream) {
  const float* feat   = (const float*)d_in[0];
  const float* logits = (const float*)d_in[1];
  const float* sx     = (const float*)d_in[2];
  const float* sy     = (const float*)d_in[3];
  const float* op     = (const float*)d_in[4];
  const float* rho    = (const float*)d_in[5];
  float* outp = (float*)d_out;
  float* acc  = (float*)d_ws;         // 196 floats (rounded to 256)
  float* MT   = acc + 256;            // 49*52 floats

  hipMemsetAsync(acc, 0, 196 * sizeof(float), stream);

  dim3 gA((NB * NQUAD + 255) / 256, 4);   // 249 x 4 class-chunks
  ga_reduce<<<gA, 256, 0, stream>>>(logits, sx, sy, op, rho, acc);
  gb_build<<<1, 64, 0, stream>>>(acc, MT);
  gc_splat<<<NB * NCH * 18, 256, 0, stream>>>(feat, MT, outp);
}

// Round 2
// 77.576 us; speedup vs baseline: 1.0872x; 1.0872x over previous
//
#include <hip/hip_runtime.h>

#define W 126
#define NPIX 15876      // 126*126
#define NQUAD 3969      // NPIX/4
#define NB 16
#define NCH 8
#define NCLS 100
#define NBLK_A 996      // 249 x-blocks * 4 class-chunks

// ws layout (floats): acc[0..255], MT[256..256+49*52), partials at 4096..
#define WS_ACC_OFF 0
#define WS_MT_OFF 256
#define WS_PART_OFF 4096

// ---------------------------------------------------------------------------
// Kernel A: contract logits over classes with (sigma_x, sigma_y, opacity, rho)
// and reduce into 196 accumulators keyed by slot = (y%7)*7 + (x%7).
// Each thread owns one float4 pixel-quad; blockIdx.y splits classes 4x25.
// Per-block result goes to a PRIVATE partials slice (no global atomics —
// the 996-deep same-address atomic chains were the 61 us stall).
// ---------------------------------------------------------------------------
__global__ __launch_bounds__(256) void ga_reduce(
    const float* __restrict__ logits,
    const float* __restrict__ sx, const float* __restrict__ sy,
    const float* __restrict__ op, const float* __restrict__ rho,
    float* __restrict__ part) {
  __shared__ float s_par[4][NCLS];
  __shared__ float s_acc[196];
  const int t = threadIdx.x;
  for (int i = t; i < NCLS; i += 256) {
    s_par[0][i] = sx[i];
    s_par[1][i] = sy[i];
    s_par[2][i] = op[i];
    s_par[3][i] = rho[i];
  }
  for (int i = t; i < 196; i += 256) s_acc[i] = 0.f;
  __syncthreads();

  const int q = blockIdx.x * 256 + t;
  if (q < NB * NQUAD) {
    const int b  = q / NQUAD;
    const int pq = q - b * NQUAD;
    const float4* base = reinterpret_cast<const float4*>(logits) +
                         (size_t)b * NCLS * NQUAD + pq;
    const int c0 = blockIdx.y * 25;
    float a00=0.f,a01=0.f,a02=0.f,a03=0.f;
    float a10=0.f,a11=0.f,a12=0.f,a13=0.f;
    float a20=0.f,a21=0.f,a22=0.f,a23=0.f;
    float a30=0.f,a31=0.f,a32=0.f,a33=0.f;
#pragma unroll
    for (int cc = 0; cc < 25; ++cc) {
      const int c = c0 + cc;
      const float4 v = base[(size_t)c * NQUAD];
      const float p0 = s_par[0][c], p1 = s_par[1][c];
      const float p2 = s_par[2][c], p3 = s_par[3][c];
      a00 += v.x*p0; a01 += v.y*p0; a02 += v.z*p0; a03 += v.w*p0;
      a10 += v.x*p1; a11 += v.y*p1; a12 += v.z*p1; a13 += v.w*p1;
      a20 += v.x*p2; a21 += v.y*p2; a22 += v.z*p2; a23 += v.w*p2;
      a30 += v.x*p3; a31 += v.y*p3; a32 += v.z*p3; a33 += v.w*p3;
    }
    const int pix = pq * 4;
    int yy = pix / W;
    int xx = pix - yy * W;
#define PUSH(A0,A1,A2,A3)                                            \
    {                                                                \
      const int slot = (yy % 7) * 7 + (xx % 7);                      \
      atomicAdd(&s_acc[slot],       A0);                             \
      atomicAdd(&s_acc[49 + slot],  A1);                             \
      atomicAdd(&s_acc[98 + slot],  A2);                             \
      atomicAdd(&s_acc[147 + slot], A3);                             \
      if (++xx == W) { xx = 0; ++yy; }                               \
    }
    PUSH(a00, a10, a20, a30)
    PUSH(a01, a11, a21, a31)
    PUSH(a02, a12, a22, a32)
    PUSH(a03, a13, a23, a33)
#undef PUSH
  }
  __syncthreads();
  float* my = part + (size_t)(blockIdx.y * 249 + blockIdx.x) * 196;
  for (int i = t; i < 196; i += 256) my[i] = s_acc[i];
}

// ---------------------------------------------------------------------------
// Kernel A2: sum the 996 per-block partials for each of the 196 accumulators.
// One wave per accumulator; shuffle reduce.
// ---------------------------------------------------------------------------
__global__ __launch_bounds__(64) void ga_final(const float* __restrict__ part,
                                               float* __restrict__ acc) {
  const int r = blockIdx.x;   // 0..195
  const int l = threadIdx.x;
  float s = 0.f;
  for (int j = l; j < NBLK_A; j += 64) s += part[(size_t)j * 196 + r];
#pragma unroll
  for (int off = 32; off; off >>= 1) s += __shfl_down(s, off);
  if (l == 0) acc[r] = s;
}

// ---------------------------------------------------------------------------
// Kernel B: per-point gaussian kernel build + bilinear shift + opacity weight.
// Writes MT[q*52 + p] = wop[p] * kt[p][q], rows padded to 52 floats.
// One block, threads p = point index (49 active).
// ---------------------------------------------------------------------------
__global__ __launch_bounds__(64) void gb_build(const float* __restrict__ acc,
                                               float* __restrict__ MT) {
  __shared__ float s_kern[49][49];  // padded 7x7 kernel per point
  const int p = threadIdx.x;
  // zero the pad columns (49..51) of each row; real columns written below
  for (int i = p; i < 49; i += 64) {
    MT[i * 52 + 49] = 0.f;
    MT[i * 52 + 50] = 0.f;
    MT[i * 52 + 51] = 0.f;
  }
  if (p < 49) {
    const float inv = 1.0f / 5184.0f;   // mean over BL = 16*18*18
    const float wsx = acc[p]        * inv;
    const float wsy = acc[49 + p]   * inv;
    const float wop = acc[98 + p]   * inv;
    const float wrh = acc[147 + p]  * inv;
    const float av = wsx * wsx + 1e-5f;
    const float dv = wsy * wsy + 1e-5f;
    const float bv = wrh * wsx * wsy;
    const float det = av * dv - bv * bv;
    const float norm = 1.0f / (6.283185307179586f * sqrtf(det));
    float tmp[5][5];
    float mx = 0.f;
#pragma unroll
    for (int i = 0; i < 5; ++i) {
      const float gx = -5.0f + 2.5f * (float)i;
#pragma unroll
      for (int j = 0; j < 5; ++j) {
        const float gy = -5.0f + 2.5f * (float)j;
        const float z = -0.5f * (dv*gx*gx - 2.0f*bv*gx*gy + av*gy*gy) / det;
        const float v = expf(z) * norm;
        tmp[i][j] = v;
        mx = fmaxf(mx, v);
      }
    }
    const float rmx = 1.0f / mx;
#pragma unroll
    for (int i = 0; i < 49; ++i) s_kern[p][i] = 0.f;
#pragma unroll
    for (int i = 0; i < 5; ++i)
#pragma unroll
      for (int j = 0; j < 5; ++j)
        s_kern[p][(i + 1) * 7 + (j + 1)] = tmp[i][j] * rmx;

    // bilinear shift (grid_sample, zeros padding, pure translation)
    const int yp = p / 7, xp = p % 7;
    const float tx = (1.0f - (2.0f * (float)xp) / 7.0f) * 3.0f;
    const float ty = (1.0f - (2.0f * (float)yp) / 7.0f) * 3.0f;
    for (int i = 0; i < 7; ++i) {
      const float yq  = (float)i + ty;
      const float y0f = floorf(yq);
      const float fy  = yq - y0f;
      const int   y0  = (int)y0f;
      for (int j = 0; j < 7; ++j) {
        const float xq  = (float)j + tx;
        const float x0f = floorf(xq);
        const float fx  = xq - x0f;
        const int   x0  = (int)x0f;
        float v = 0.f;
        for (int dy = 0; dy < 2; ++dy) {
          const int yi = y0 + dy;
          if (yi < 0 || yi > 6) continue;
          const float wy = dy ? fy : (1.0f - fy);
          for (int dx = 0; dx < 2; ++dx) {
            const int xi = x0 + dx;
            if (xi < 0 || xi > 6) continue;
            const float wx = dx ? fx : (1.0f - fx);
            v += wy * wx * s_kern[p][yi * 7 + xi];
          }
        }
        MT[(i * 7 + j) * 52 + p] = wop * v;
      }
    }
  }
}

// ---------------------------------------------------------------------------
// Kernel C: splat. One block per (plane, patch-row) strip of 7x126 pixels.
// out[q] = dot49(feat_patch, MT_row[q]); both staged in LDS, float4 reads.
// ---------------------------------------------------------------------------
__global__ __launch_bounds__(256) void gc_splat(
    const float* __restrict__ feat, const float* __restrict__ MT,
    float* __restrict__ out) {
  __shared__ __align__(16) float s_mt[49 * 52];
  __shared__ __align__(16) float s_fp[18 * 52];
  const int t = threadIdx.x;
  for (int i = t; i < 49 * 52; i += 256) s_mt[i] = MT[i];
  const int blk   = blockIdx.x;           // plane*18 + patch_row
  const int plane = blk / 18;
  const int pr    = blk - plane * 18;
  const float* src = feat + (size_t)plane * NPIX + (size_t)pr * 7 * W;
  for (int i = t; i < 882; i += 256) {
    const int py = i / W;
    const int xx = i - py * W;
    const int pc = xx / 7;
    const int px = xx - pc * 7;
    s_fp[pc * 52 + py * 7 + px] = src[i];
  }
  __syncthreads();
  float* dst = out + (size_t)plane * NPIX + (size_t)pr * 7 * W;
  for (int i = t; i < 882; i += 256) {
    const int yy = i / W;
    const int xx = i - yy * W;
    const int pc = xx / 7;
    const int q  = yy * 7 + (xx - pc * 7);
    const float4* mv = reinterpret_cast<const float4*>(s_mt + q * 52);
    const float4* fv = reinterpret_cast<const float4*>(s_fp + pc * 52);
    float s = 0.f;
#pragma unroll
    for (int r = 0; r < 12; ++r) {
      const float4 m = mv[r];
      const float4 f = fv[r];
      s += f.x * m.x + f.y * m.y + f.z * m.z + f.w * m.w;
    }
    s += s_fp[pc * 52 + 48] * s_mt[q * 52 + 48];
    dst[i] = s;
  }
}

extern "C" void kernel_launch(void* const* d_in, const int* in_sizes, int n_in,
                              void* d_out, int out_size, void* d_ws, size_t ws_size,
                              hipStream_t stream) {
  const float* feat   = (const float*)d_in[0];
  const float* logits = (const float*)d_in[1];
  const float* sx     = (const float*)d_in[2];
  const float* sy     = (const float*)d_in[3];
  const float* op     = (const float*)d_in[4];
  const float* rho    = (const float*)d_in[5];
  float* outp = (float*)d_out;
  float* ws   = (float*)d_ws;
  float* acc  = ws + WS_ACC_OFF;      // 196 floats
  float* MT   = ws + WS_MT_OFF;       // 49*52 floats
  float* part = ws + WS_PART_OFF;     // 996*196 floats (~780 KB)

  dim3 gA((NB * NQUAD + 255) / 256, 4);   // 249 x 4 class-chunks
  ga_reduce<<<gA, 256, 0, stream>>>(logits, sx, sy, op, rho, part);
  ga_final<<<196, 64, 0, stream>>>(part, acc);
  gb_build<<<1, 64, 0, stream>>>(acc, MT);
  gc_splat<<<NB * NCH * 18, 256, 0, stream>>>(feat, MT, outp);
}